// Round 1
// baseline (211.958 us; speedup 1.0000x reference)
//
#include <hip/hip_runtime.h>

// Problem constants
#define B_ 64
#define T_ 512
#define D_ 1024
#define S_ 1024
#define U_ 10

typedef float f32x2 __attribute__((ext_vector_type(2)));
typedef float f32x4 __attribute__((ext_vector_type(4)));

// workspace layout (in floats)
static constexpr int WS_PMZ = 0;        // [512][2]  per-block partial (m, Z)
static constexpr int WS_E   = 1024;     // [64][512] raw e values
static constexpr int WS_PV  = 33792;    // [512][1024] per-block partial weighted sums

// ---------------------------------------------------------------------------
// DPP wave64 sum -> uniform (SGPR) value. No DS ops.
// ---------------------------------------------------------------------------
template <int CTRL>
__device__ __forceinline__ float dpp_add(float x) {
    int yi = __builtin_amdgcn_update_dpp(0, __float_as_int(x), CTRL, 0xf, 0xf, true);
    return x + __int_as_float(yi);
}

__device__ __forceinline__ float wave_sum_uniform(float x) {
    x = dpp_add<0x111>(x);   // row_shr:1
    x = dpp_add<0x112>(x);   // row_shr:2
    x = dpp_add<0x114>(x);   // row_shr:4
    x = dpp_add<0x118>(x);   // row_shr:8
    x = dpp_add<0x142>(x);   // row_bcast15
    x = dpp_add<0x143>(x);   // row_bcast31 -> lane 63 = total
    return __int_as_float(__builtin_amdgcn_readlane(__float_as_int(x), 63));
}

__device__ __forceinline__ float uload(const float* p) {
    return __int_as_float(__builtin_amdgcn_readfirstlane(__float_as_int(*p)));
}
__device__ __forceinline__ float uniformf(float x) {
    return __int_as_float(__builtin_amdgcn_readfirstlane(__float_as_int(x)));
}

// packed 2xf32 fma -> v_pk_fma_f32 on gfx950 (packed FP32 ops); scalarizes if not.
__device__ __forceinline__ f32x2 pk_fma(f32x2 a, f32x2 b, f32x2 c) {
#if __has_builtin(__builtin_elementwise_fma)
    return __builtin_elementwise_fma(a, b, c);
#else
    return a * b + c;   // -ffp-contract=fast contracts to fma
#endif
}

// ---------------------------------------------------------------------------
// K1: fused main pass. 512 blocks = 64 batches x 8 t-chunks of 64.
// 4 waves/block, each wave owns 16 consecutive t; lane owns 16 d's.
// Phase A: wave redundantly computes c[u] = s_prev[b]·W1[D:,u] + b1[u] (SGPRs).
// Phase B: online softmax over t, packed-f32 matmul, deferred rescale.
// ---------------------------------------------------------------------------
__global__ __launch_bounds__(256, 2) void k1_main(const float* __restrict__ a,
                                                  const float* __restrict__ s_prev,
                                                  const float* __restrict__ W1,
                                                  const float* __restrict__ b1,
                                                  const float* __restrict__ W2,
                                                  const float* __restrict__ b2,
                                                  float* __restrict__ ws) {
    const int blk  = blockIdx.x;
    const int b    = blk >> 3;
    const int p    = blk & 7;
    const int tid  = threadIdx.x;
    const int wave = tid >> 6;
    const int lane = tid & 63;

    // ---- Phase A: per-wave c[u], forced uniform (SGPR-resident) ----
    float c[U_];
    {
        float cacc[U_];
#pragma unroll
        for (int u = 0; u < U_; u++) cacc[u] = 0.f;
#pragma unroll
        for (int r = 0; r < 4; r++) {
            const f32x4 s4 = *(const f32x4*)(s_prev + b * S_ + r * 256 + lane * 4);
            const float svv[4] = {s4.x, s4.y, s4.z, s4.w};
#pragma unroll
            for (int i = 0; i < 4; i++) {
                const int s = r * 256 + lane * 4 + i;
                const float* wp = W1 + (size_t)(D_ + s) * U_;   // 8B-aligned
#pragma unroll
                for (int h = 0; h < 5; h++) {
                    f32x2 t = *(const f32x2*)(wp + 2 * h);
                    cacc[2 * h]     += svv[i] * t.x;
                    cacc[2 * h + 1] += svv[i] * t.y;
                }
            }
        }
#pragma unroll
        for (int u = 0; u < U_; u++)
            c[u] = uniformf(wave_sum_uniform(cacc[u]) + uload(b1 + u));
    }

    float w2v[U_];
#pragma unroll
    for (int u = 0; u < U_; u++) w2v[u] = uload(W2 + u);   // SGPR
    const float b2s = uload(b2);                           // SGPR

    // ---- W1[:D] fragment as packed d-pairs: w1p[k][pp][u] = (W1[d0+2pp], W1[d0+2pp+1]) ----
    f32x2 w1p[4][2][U_];   // 160 VGPRs
#pragma unroll
    for (int k = 0; k < 4; k++) {
        const float* wp = W1 + (size_t)(k * 256 + lane * 4) * U_;   // 16B-aligned (40*4B rows x4)
        float wbuf[40];
#pragma unroll
        for (int q = 0; q < 10; q++) {
            f32x4 t = *(const f32x4*)(wp + 4 * q);
            wbuf[4 * q + 0] = t.x; wbuf[4 * q + 1] = t.y;
            wbuf[4 * q + 2] = t.z; wbuf[4 * q + 3] = t.w;
        }
#pragma unroll
        for (int u = 0; u < U_; u++) {
            w1p[k][0][u] = f32x2{wbuf[u],      wbuf[10 + u]};
            w1p[k][1][u] = f32x2{wbuf[20 + u], wbuf[30 + u]};
        }
    }

    // ---- Phase B: online softmax over 16 t, ping-pong prefetch ----
    f32x2 v2[4][2];
#pragma unroll
    for (int k = 0; k < 4; k++) { v2[k][0] = 0.f; v2[k][1] = 0.f; }
    float m = -1e30f, Z = 0.f;

    const int t0 = p * 64 + wave * 16;
    const float* abase = a + ((size_t)(b * T_ + t0)) * D_ + lane * 4;

    f32x4 bufA[4], bufB[4];
#pragma unroll
    for (int k = 0; k < 4; k++) bufA[k] = *(const f32x4*)(abase + k * 256);

    auto calc_e = [&](const f32x4* buf) -> float {
        f32x2 acc2[U_];
#pragma unroll
        for (int u = 0; u < U_; u++) acc2[u] = 0.f;
#pragma unroll
        for (int k = 0; k < 4; k++) {
            const f32x2 alo = buf[k].lo;
            const f32x2 ahi = buf[k].hi;
#pragma unroll
            for (int u = 0; u < U_; u++) {
                acc2[u] = pk_fma(alo, w1p[k][0][u], acc2[u]);
                acc2[u] = pk_fma(ahi, w1p[k][1][u], acc2[u]);
            }
        }
        float tm[U_];
#pragma unroll
        for (int u = 0; u < U_; u++) {
            float s = wave_sum_uniform(acc2[u].x + acc2[u].y);
            float x = s + c[u];
            // tanh(x) = 1 - 2/(e^{2x}+1); exp2 saturates -> exact +-1 tails, no clamp
            float ex = exp2f(x * 2.8853900817779268f);
            float th = 1.f - 2.f * __builtin_amdgcn_rcpf(ex + 1.f);
            tm[u] = th * w2v[u];
        }
        float e = ((tm[0] + tm[1]) + (tm[2] + tm[3])) +
                  ((tm[4] + tm[5]) + (tm[6] + tm[7])) +
                  ((tm[8] + tm[9]) + b2s);
        return fmaxf(e, 0.f);
    };

    auto step = [&](const f32x4* buf, int tt) {
        float e = calc_e(buf);
        if (lane == 0) ws[WS_E + b * T_ + t0 + tt] = e;
        if (e > m) {
            // new max: w = exp(e-e) = 1, rescale old state (rare: ~H(16) times)
            float sc = exp2f((m - e) * 1.4426950408889634f);
            Z = Z * sc + 1.f;
            f32x2 scv = {sc, sc};
#pragma unroll
            for (int k = 0; k < 4; k++) {
                v2[k][0] = pk_fma(v2[k][0], scv, buf[k].lo);
                v2[k][1] = pk_fma(v2[k][1], scv, buf[k].hi);
            }
            m = e;
        } else {
            // common path: no rescale
            float w = exp2f((e - m) * 1.4426950408889634f);
            Z += w;
            f32x2 wv = {w, w};
#pragma unroll
            for (int k = 0; k < 4; k++) {
                v2[k][0] = pk_fma(wv, buf[k].lo, v2[k][0]);
                v2[k][1] = pk_fma(wv, buf[k].hi, v2[k][1]);
            }
        }
    };

#pragma unroll 1
    for (int tt = 0; tt < 16; tt += 2) {
        const float* apB = abase + (size_t)(tt + 1) * D_;
#pragma unroll
        for (int k = 0; k < 4; k++) bufB[k] = *(const f32x4*)(apB + k * 256);
        step(bufA, tt);
        if (tt < 14) {
            const float* apA = abase + (size_t)(tt + 2) * D_;
#pragma unroll
            for (int k = 0; k < 4; k++) bufA[k] = *(const f32x4*)(apA + k * 256);
        }
        step(bufB, tt + 1);
    }

    // ---- block combine across 4 waves ----
    __shared__ f32x4 vs4[4][256];
    __shared__ float mzs[4][2];
#pragma unroll
    for (int k = 0; k < 4; k++) {
        f32x4 o;
        o.lo = v2[k][0];
        o.hi = v2[k][1];
        vs4[wave][k * 64 + lane] = o;
    }
    if (lane == 0) { mzs[wave][0] = m; mzs[wave][1] = Z; }
    __syncthreads();

    float m0 = mzs[0][0], m1 = mzs[1][0], m2 = mzs[2][0], m3 = mzs[3][0];
    float mb = fmaxf(fmaxf(m0, m1), fmaxf(m2, m3));
    float f0 = __expf(m0 - mb), f1 = __expf(m1 - mb);
    float f2 = __expf(m2 - mb), f3 = __expf(m3 - mb);
    float Zb = f0 * mzs[0][1] + f1 * mzs[1][1] + f2 * mzs[2][1] + f3 * mzs[3][1];

    f32x4 t0v = vs4[0][tid], t1v = vs4[1][tid], t2v = vs4[2][tid], t3v = vs4[3][tid];
    f32x4 o = f0 * t0v + f1 * t1v + f2 * t2v + f3 * t3v;
    ((f32x4*)(ws + WS_PV))[blk * 256 + tid] = o;
    if (tid == 0) { ws[WS_PMZ + blk * 2] = mb; ws[WS_PMZ + blk * 2 + 1] = Zb; }
}

// ---------------------------------------------------------------------------
// K2: final combine per batch (8 partials) -> context + scores
// ---------------------------------------------------------------------------
__global__ __launch_bounds__(256) void k2_final(const float* __restrict__ ws,
                                                float* __restrict__ out) {
    const int b = blockIdx.x;
    const int tid = threadIdx.x;

    float pm[8], pz[8];
    float mb = -1e30f;
#pragma unroll
    for (int p = 0; p < 8; p++) {
        pm[p] = ws[WS_PMZ + (b * 8 + p) * 2];
        pz[p] = ws[WS_PMZ + (b * 8 + p) * 2 + 1];
        mb = fmaxf(mb, pm[p]);
    }
    float f[8], Z = 0.f;
#pragma unroll
    for (int p = 0; p < 8; p++) { f[p] = __expf(pm[p] - mb); Z += f[p] * pz[p]; }
    const float rz = 1.f / Z;

    float4 o = make_float4(0.f, 0.f, 0.f, 0.f);
#pragma unroll
    for (int p = 0; p < 8; p++) {
        float4 t = ((const float4*)(ws + WS_PV))[(b * 8 + p) * 256 + tid];
        o.x += f[p] * t.x; o.y += f[p] * t.y; o.z += f[p] * t.z; o.w += f[p] * t.w;
    }
    o.x *= rz; o.y *= rz; o.z *= rz; o.w *= rz;
    ((float4*)out)[b * 256 + tid] = o;

    for (int t = tid; t < T_; t += 256) {
        out[B_ * D_ + b * T_ + t] = __expf(ws[WS_E + b * T_ + t] - mb) * rz;
    }
}

// ---------------------------------------------------------------------------
extern "C" void kernel_launch(void* const* d_in, const int* in_sizes, int n_in,
                              void* d_out, int out_size, void* d_ws, size_t ws_size,
                              hipStream_t stream) {
    const float* a      = (const float*)d_in[0];
    const float* s_prev = (const float*)d_in[1];
    const float* W1     = (const float*)d_in[2];
    const float* b1     = (const float*)d_in[3];
    const float* W2     = (const float*)d_in[4];
    const float* b2     = (const float*)d_in[5];
    float* out = (float*)d_out;
    float* ws  = (float*)d_ws;

    k1_main<<<dim3(B_ * 8), dim3(256), 0, stream>>>(a, s_prev, W1, b1, W2, b2, ws);
    k2_final<<<dim3(B_), dim3(256), 0, stream>>>(ws, out);
}